// Round 10
// baseline (85.884 us; speedup 1.0000x reference)
//
#include <hip/hip_runtime.h>

// n=4, L=8192, h=8, e=64, fp32 in/out
#define N_      4
#define L_      8192
#define H_      8
#define E_      64
#define NH_     (N_ * H_)
#define ROWF_   512                // floats per s-row (8 heads x 64)
#define CKB_    64                 // blocks per n  -> grid 4*64 = 256
#define RPB_    128                // s-rows per block (2 chunks of 64)

// ws (floats): pkv[256][8][4096] | pks[256][512] | kvt bf16[NH_][4096] | ksum[NH_][64]
#define PKV_F  ((size_t)N_ * CKB_ * H_ * E_ * E_)   // 32 MB
#define PKS_F  ((size_t)N_ * CKB_ * H_ * E_)        // 512 KB
#define KVT_F  ((size_t)NH_ * E_ * E_ / 2)
#define PKS_OFF  PKV_F
#define KVT_OFF  (PKV_F + PKS_F)
#define KSUM_OFF (KVT_OFF + KVT_F)

typedef short bf16x8 __attribute__((ext_vector_type(8)));
typedef float f32x16 __attribute__((ext_vector_type(16)));

__device__ __forceinline__ float featmap(float x) {
    float xs = x * 0.35355339059327373f;   // * 64^-0.25
    return xs > 0.0f ? xs + 1.0f : __expf(xs);
}
__device__ __forceinline__ unsigned short f2bf(float f) {   // RNE f32->bf16
    union { float f; unsigned u; } c{f};
    unsigned r = c.u + 0x7FFFu + ((c.u >> 16) & 1u);
    return (unsigned short)(r >> 16);
}
__device__ __forceinline__ unsigned cvt_pk_bf16(float lo, float hi) {
    unsigned r;
    asm("v_cvt_pk_bf16_f32 %0, %1, %2" : "=v"(r) : "v"(lo), "v"(hi));
    return r;
}

// ---------------------------------------------------------------------------
// Phase 1 (DENSE + r8-proven swizzle): each block reads FULL 2 KB rows (all
// 8 heads) of its 128-row s-range; 2 chunks of 64 rows, single-buffered
// 128 KB LDS. Staging: thread t -> (sp_off=t&3, f4col=t>>2): sp varies in
// low lane bits => LDS writes span all 32 banks; loads are 4x256B dense
// segments per instruction. Swizzle (verbatim r8, numerically validated):
// u32 idx [h][d][slot*4 + (sp&3)], slot = (sp>>2)^(d&7)^((d>>2)&7); read
// sa = ((2m+lh)^(lm&7)^(lm>>2))&7 -> retrieved k-order is canonical
// s=16m+8lh+j for EVERY lane (A and B identical) so MFMA contracts matched s.
// Wave w computes head w's full 64x64 (4 quadrants x 4 ksteps = 16 MFMA).
// ---------------------------------------------------------------------------
__global__ __launch_bounds__(512) void la_kv(
    const float* __restrict__ keys, const float* __restrict__ values,
    float* __restrict__ pkv, float* __restrict__ pks)
{
    const int blk = blockIdx.x;
    const int n = blk / CKB_, cki = blk % CKB_;
    const int t = threadIdx.x, l = t & 63, w = t >> 6;
    const int lm = l & 31, lh = l >> 5;
    const int spo = t & 3;           // sp offset within sub-round
    const int c4  = t >> 2;          // 0..127 float4-col
    const int sh  = c4 >> 4;         // staging head 0..7
    const int sd0 = 4 * (c4 & 15);   // staging d base

    __shared__ unsigned Kb[H_][E_][32];   // 64 KB
    __shared__ unsigned Vb[H_][E_][32];   // 64 KB

    f32x16 acc[4];
    #pragma unroll
    for (int q = 0; q < 4; ++q)
        acc[q] = (f32x16){0,0,0,0,0,0,0,0,0,0,0,0,0,0,0,0};
    float ksp[4] = {0.f, 0.f, 0.f, 0.f};

    const size_t rowbase = ((size_t)n * L_ + (size_t)cki * RPB_) * ROWF_ + 4 * c4;
    float4 kld[2][2], vld[2][2];

#define LOADSR(CH, SR, B) {                                                   \
    const size_t o_ = rowbase + (size_t)((CH) * 64 + (SR) * 8 + 2 * spo) * ROWF_; \
    kld[B][0] = *(const float4*)(keys + o_);                                  \
    kld[B][1] = *(const float4*)(keys + o_ + ROWF_);                          \
    vld[B][0] = *(const float4*)(values + o_);                                \
    vld[B][1] = *(const float4*)(values + o_ + ROWF_); }

#define STORESR(SR, B) {                                                      \
    const float fe_[4] = {featmap(kld[B][0].x), featmap(kld[B][0].y),         \
                          featmap(kld[B][0].z), featmap(kld[B][0].w)};        \
    const float fo_[4] = {featmap(kld[B][1].x), featmap(kld[B][1].y),         \
                          featmap(kld[B][1].z), featmap(kld[B][1].w)};        \
    const float ve_[4] = {vld[B][0].x, vld[B][0].y, vld[B][0].z, vld[B][0].w};\
    const float vo_[4] = {vld[B][1].x, vld[B][1].y, vld[B][1].z, vld[B][1].w};\
    _Pragma("unroll")                                                         \
    for (int j_ = 0; j_ < 4; ++j_) {                                          \
        ksp[j_] += fe_[j_] + fo_[j_];                                         \
        const int d_ = sd0 + j_;                                              \
        const int sl_ = ((SR) ^ (d_ & 7) ^ ((d_ >> 2) & 7)) & 7;              \
        Kb[sh][d_][sl_ * 4 + spo] = cvt_pk_bf16(fe_[j_], fo_[j_]);            \
        Vb[sh][d_][sl_ * 4 + spo] = cvt_pk_bf16(ve_[j_], vo_[j_]); } }

#define COMPUTECH() {                                                         \
    _Pragma("unroll")                                                         \
    for (int m_ = 0; m_ < 4; ++m_) {                                          \
        const int sa_ = ((2 * m_ + lh) ^ (lm & 7) ^ (lm >> 2)) & 7;           \
        bf16x8 a0_ = *(const bf16x8*)&Kb[w][lm][sa_ * 4];                     \
        bf16x8 a1_ = *(const bf16x8*)&Kb[w][32 + lm][sa_ * 4];                \
        bf16x8 b0_ = *(const bf16x8*)&Vb[w][lm][sa_ * 4];                     \
        bf16x8 b1_ = *(const bf16x8*)&Vb[w][32 + lm][sa_ * 4];                \
        acc[0] = __builtin_amdgcn_mfma_f32_32x32x16_bf16(a0_, b0_, acc[0], 0, 0, 0); \
        acc[1] = __builtin_amdgcn_mfma_f32_32x32x16_bf16(a0_, b1_, acc[1], 0, 0, 0); \
        acc[2] = __builtin_amdgcn_mfma_f32_32x32x16_bf16(a1_, b0_, acc[2], 0, 0, 0); \
        acc[3] = __builtin_amdgcn_mfma_f32_32x32x16_bf16(a1_, b1_, acc[3], 0, 0, 0); } }

    // ---- chunk 0 ----
    LOADSR(0, 0, 0);
    #pragma unroll
    for (int sr = 0; sr < 8; ++sr) {
        if (sr < 7) { LOADSR(0, sr + 1, (sr + 1) & 1); }
        else        { LOADSR(1, 0, 0); }         // chunk-1 prefetch (buf (8)&1=0)
        STORESR(sr, sr & 1);
    }
    __syncthreads();
    COMPUTECH();
    __syncthreads();
    // ---- chunk 1 ----
    #pragma unroll
    for (int sr = 0; sr < 8; ++sr) {
        if (sr < 7) { LOADSR(1, sr + 1, (sr + 1) & 1); }
        STORESR(sr, sr & 1);
    }
    __syncthreads();
    COMPUTECH();
#undef LOADSR
#undef STORESR
#undef COMPUTECH

    // C/D write (m74/m101): col=lane&31, row=(r&3)+8*(r>>2)+4*(lane>>5)
    float* dst = pkv + ((size_t)blk * H_ + w) * (E_ * E_);
    #pragma unroll
    for (int q = 0; q < 4; ++q) {
        const int wd = q >> 1, wm = q & 1;
        #pragma unroll
        for (int r = 0; r < 16; ++r) {
            const int ro = (r & 3) + 8 * (r >> 2) + 4 * lh;
            dst[(32 * wd + ro) * E_ + 32 * wm + lm] = acc[q][r];
        }
    }

    // ksum: per-thread partials (16 rows x 4 d each, both chunks) -> LDS
    // scratch (reuse Kb after all reads done) -> 4-way reduce -> pks.
    __syncthreads();
    float* ksb = (float*)&Kb[0][0][0];          // [512][4] f32 = 8 KB
    *(float4*)&ksb[t * 4] = make_float4(ksp[0], ksp[1], ksp[2], ksp[3]);
    __syncthreads();
    {
        const int hq = t >> 6, dq = t & 63;      // output (h, d)
        const int c4r = (hq << 4) | (dq >> 2), jr = dq & 3;
        float s = ksb[(c4r * 4 + 0) * 4 + jr] + ksb[(c4r * 4 + 1) * 4 + jr]
                + ksb[(c4r * 4 + 2) * 4 + jr] + ksb[(c4r * 4 + 3) * 4 + jr];
        pks[(size_t)blk * 512 + t] = s;
    }
}

// ---------------------------------------------------------------------------
// Reduce: KV[nh][d][m] = sum over 64 chunk-blocks; emit KV^T bf16 + ksum f32.
// ---------------------------------------------------------------------------
__global__ __launch_bounds__(256) void la_reduce(
    const float* __restrict__ pkv, const float* __restrict__ pks,
    unsigned short* __restrict__ kvt, float* __restrict__ ksum)
{
    const int b = blockIdx.x, nh = b >> 4, sl = b & 15;
    const int n2 = nh >> 3, h = nh & 7;
    const int e = sl * 256 + threadIdx.x;       // e = d*64 + m
    const float* src = pkv + ((size_t)(n2 * CKB_) * H_ + h) * (E_ * E_) + e;
    float s = 0.f;
    #pragma unroll
    for (int c2 = 0; c2 < CKB_; ++c2) s += src[(size_t)c2 * H_ * (E_ * E_)];
    const int d = e >> 6, m = e & 63;
    kvt[(size_t)nh * (E_ * E_) + m * E_ + d] = f2bf(s);

    if (sl == 0 && threadIdx.x < E_) {
        const float* sp = pks + (size_t)(n2 * CKB_) * 512 + h * E_ + threadIdx.x;
        float ss = 0.f;
        #pragma unroll
        for (int c2 = 0; c2 < CKB_; ++c2) ss += sp[(size_t)c2 * 512];
        ksum[nh * E_ + threadIdx.x] = ss;
    }
}

// ---------------------------------------------------------------------------
// Phase 2: out[l][m] = z[l] * sum_d qf[l,d]*KV[d,m] via MFMA (r8, unchanged).
// ---------------------------------------------------------------------------
__global__ __launch_bounds__(256) void la_out(
    const float* __restrict__ q, const unsigned short* __restrict__ kvt,
    const float* __restrict__ ksum, float* __restrict__ out)
{
    const int blk = blockIdx.x, nh = blk >> 5, tile = blk & 31;
    const int n = nh / H_, h = nh % H_;
    const int t = threadIdx.x, l = t & 63, w = t >> 6;
    const int lm = l & 31, lh = l >> 5;

    __shared__ float zbuf[4][32];

    const unsigned short* kb = kvt + (size_t)nh * (E_ * E_);
    const float* ks = ksum + nh * E_;

    bf16x8 bfr[4][2];
    float4 kr[4][2];
    #pragma unroll
    for (int st = 0; st < 4; ++st) {
        #pragma unroll
        for (int c = 0; c < 2; ++c)
            bfr[st][c] = *(const bf16x8*)&kb[(32 * c + lm) * E_ + st * 16 + 8 * lh];
        kr[st][0] = *(const float4*)&ks[st * 16 + 8 * lh];
        kr[st][1] = *(const float4*)&ks[st * 16 + 8 * lh + 4];
    }

    const size_t base = (size_t)n * (L_ * H_ * E_) + (size_t)h * E_;

    #pragma unroll
    for (int bnd = 0; bnd < 2; ++bnd) {
        const int l0 = tile * 256 + w * 64 + bnd * 32;
        const float* qp = q + base + (size_t)(l0 + lm) * (H_ * E_) + 8 * lh;

        float4 qa[4], qb[4];
        #pragma unroll
        for (int st = 0; st < 4; ++st) {
            qa[st] = *(const float4*)(qp + st * 16);
            qb[st] = *(const float4*)(qp + st * 16 + 4);
        }

        float zd = 0.f;
        bf16x8 af[4];
        #pragma unroll
        for (int st = 0; st < 4; ++st) {
            const float f0 = featmap(qa[st].x), f1 = featmap(qa[st].y),
                        f2 = featmap(qa[st].z), f3 = featmap(qa[st].w);
            const float g0 = featmap(qb[st].x), g1 = featmap(qb[st].y),
                        g2 = featmap(qb[st].z), g3 = featmap(qb[st].w);
            zd += f0 * kr[st][0].x + f1 * kr[st][0].y + f2 * kr[st][0].z + f3 * kr[st][0].w
                + g0 * kr[st][1].x + g1 * kr[st][1].y + g2 * kr[st][1].z + g3 * kr[st][1].w;
            union { bf16x8 v; unsigned u[4]; } a;
            a.u[0] = cvt_pk_bf16(f0, f1);
            a.u[1] = cvt_pk_bf16(f2, f3);
            a.u[2] = cvt_pk_bf16(g0, g1);
            a.u[3] = cvt_pk_bf16(g2, g3);
            af[st] = a.v;
        }
        zd += __shfl_xor(zd, 32);
        const float z = 1.0f / (zd + 1e-6f);
        if (l < 32) zbuf[w][l] = z;
        __builtin_amdgcn_wave_barrier();

        f32x16 c0 = {0,0,0,0,0,0,0,0,0,0,0,0,0,0,0,0};
        f32x16 c1 = {0,0,0,0,0,0,0,0,0,0,0,0,0,0,0,0};
        #pragma unroll
        for (int st = 0; st < 4; ++st) {
            c0 = __builtin_amdgcn_mfma_f32_32x32x16_bf16(af[st], bfr[st][0], c0, 0, 0, 0);
            c1 = __builtin_amdgcn_mfma_f32_32x32x16_bf16(af[st], bfr[st][1], c1, 0, 0, 0);
        }

        float* op = out + base + (size_t)l0 * (H_ * E_) + lm;
        #pragma unroll
        for (int r = 0; r < 16; ++r) {
            const int ro = (r & 3) + 8 * (r >> 2) + 4 * lh;
            const float zz = zbuf[w][ro];
            op[(size_t)ro * (H_ * E_)]      = c0[r] * zz;
            op[(size_t)ro * (H_ * E_) + 32] = c1[r] * zz;
        }
        __builtin_amdgcn_wave_barrier();   // zbuf reused next band
    }
}

extern "C" void kernel_launch(void* const* d_in, const int* in_sizes, int n_in,
                              void* d_out, int out_size, void* d_ws, size_t ws_size,
                              hipStream_t stream) {
    (void)in_sizes; (void)n_in; (void)out_size; (void)ws_size;
    const float* qq = (const float*)d_in[0];
    const float* kk = (const float*)d_in[1];
    const float* vv = (const float*)d_in[2];
    float* outp = (float*)d_out;
    float* ws   = (float*)d_ws;

    float* pkv = ws;
    float* pks = ws + PKS_OFF;
    unsigned short* kvt = (unsigned short*)(ws + KVT_OFF);
    float* ksm = ws + KSUM_OFF;

    la_kv<<<N_ * CKB_, 512, 0, stream>>>(kk, vv, pkv, pks);
    la_reduce<<<NH_ * 16, 256, 0, stream>>>(pkv, pks, kvt, ksm);
    la_out<<<NH_ * 32, 256, 0, stream>>>(qq, kvt, ksm, outp);
}

// Round 12
// 67.822 us; speedup vs baseline: 1.2663x; 1.2663x over previous
//
#include <hip/hip_runtime.h>

// n=4, L=8192, h=8, e=64, fp32 in/out
#define N_      4
#define L_      8192
#define H_      8
#define E_      64
#define NH_     (N_ * H_)
#define STRIDE_ (H_ * E_)          // 512 floats between rows
#define SPLIT_  32                 // s-split for phase 1 (1024 blocks)
#define RPB_    (L_ / SPLIT_)      // 256 rows per block
#define CHR_    64                 // rows per staged chunk
#define NCHK_   (RPB_ / CHR_)      // 4 chunks

typedef short bf16x8 __attribute__((ext_vector_type(8)));
typedef float f32x16 __attribute__((ext_vector_type(16)));

__device__ __forceinline__ float featmap(float x) {
    float xs = x * 0.35355339059327373f;   // * 64^-0.25
    return xs > 0.0f ? xs + 1.0f : __expf(xs);
}
__device__ __forceinline__ unsigned short f2bf(float f) {   // RNE f32->bf16
    union { float f; unsigned u; } c{f};
    unsigned r = c.u + 0x7FFFu + ((c.u >> 16) & 1u);
    return (unsigned short)(r >> 16);
}
__device__ __forceinline__ unsigned cvt_pk_bf16(float lo, float hi) {
    unsigned r;
    asm("v_cvt_pk_bf16_f32 %0, %1, %2" : "=v"(r) : "v"(lo), "v"(hi));
    return r;
}
// XOR swizzle slot (r8-proven): element pair (d, sp=s/2) lives at u32 index
// d*32 + slot*4 + (sp&3), slot = (sp>>2)^(d&7)^((d>>2)&7).
__device__ __forceinline__ int swz_slot(int d, int sp4) {   // sp4 = sp>>2
    return (sp4 ^ (d & 7) ^ ((d >> 2) & 7)) & 7;
}

// ---------------------------------------------------------------------------
// Phase 1: KV_partial[d][m] = sum_s kf[s,d]*v[s,m] via bf16 MFMA 32x32x16.
// r8's kernel VERBATIM except the chunk loop order. Old order issued the
// next chunk's global loads BEFORE __syncthreads(); the compiler emits
// s_waitcnt vmcnt(0) before s_barrier, so the prefetch was drained at every
// barrier -> zero pipeline depth (the structure-invariant ~60 us wall).
// New order: STORE(c) -> barrier (free drain: nothing outstanding) ->
// issue LOAD(c+1) -> COMPUTE(c). Loads stay in flight across ~500 cy of
// ds_read+MFMA and are consumed by the next STORE's counted vmcnt.
// Dbuf safety: STORE(c+1) targets buf^1 only after barrier(c); every wave
// finished COMPUTE(c-1) (reads of buf^1) before reaching barrier(c).
// ---------------------------------------------------------------------------
__global__ __launch_bounds__(256) void la_kv(
    const float* __restrict__ keys, const float* __restrict__ values,
    float* __restrict__ pkv, float* __restrict__ pks)
{
    const int blk = blockIdx.x;
    const int nh = blk / SPLIT_, chunk = blk % SPLIT_;
    const int n = nh / H_, h = nh % H_;
    const int t = threadIdx.x, l = t & 63;
    const int w = t >> 6, wd = w >> 1, wm = w & 1;
    const int lm = l & 31, lh = l >> 5;
    const int pr = t >> 3, c = t & 7;      // row-pair 0..31, col-octet 0..7

    __shared__ unsigned Kb[2][CHR_][32];   // [buf][d][swizzled s-pair] 16 KB
    __shared__ unsigned Vb[2][CHR_][32];   // 16 KB

    f32x16 acc = {0,0,0,0,0,0,0,0,0,0,0,0,0,0,0,0};
    float ksp[8] = {0.f,0.f,0.f,0.f,0.f,0.f,0.f,0.f};

    const size_t base = (size_t)n * (L_ * H_ * E_) + (size_t)h * E_;
    // rows 2pr/2pr+1 of the chunk, cols 4c..4c+3 and 32+4c..32+4c+3
    const size_t rbase = base + (size_t)(chunk * RPB_ + 2 * pr) * STRIDE_ + 4 * c;

    float4 kr0 = *(const float4*)(keys + rbase);
    float4 kr1 = *(const float4*)(keys + rbase + 32);
    float4 kr2 = *(const float4*)(keys + rbase + STRIDE_);
    float4 kr3 = *(const float4*)(keys + rbase + STRIDE_ + 32);
    float4 vr0 = *(const float4*)(values + rbase);
    float4 vr1 = *(const float4*)(values + rbase + 32);
    float4 vr2 = *(const float4*)(values + rbase + STRIDE_);
    float4 vr3 = *(const float4*)(values + rbase + STRIDE_ + 32);

    #pragma unroll
    for (int ch = 0; ch < NCHK_; ++ch) {
        const int buf = ch & 1;
        float a0[4] = {kr0.x, kr0.y, kr0.z, kr0.w};
        float a1[4] = {kr1.x, kr1.y, kr1.z, kr1.w};
        float a2[4] = {kr2.x, kr2.y, kr2.z, kr2.w};
        float a3[4] = {kr3.x, kr3.y, kr3.z, kr3.w};
        float b0[4] = {vr0.x, vr0.y, vr0.z, vr0.w};
        float b1[4] = {vr1.x, vr1.y, vr1.z, vr1.w};
        float b2[4] = {vr2.x, vr2.y, vr2.z, vr2.w};
        float b3[4] = {vr3.x, vr3.y, vr3.z, vr3.w};

        #pragma unroll
        for (int i = 0; i < 4; ++i) {
            const float f0 = featmap(a0[i]), f1 = featmap(a1[i]);
            const float f2 = featmap(a2[i]), f3 = featmap(a3[i]);
            ksp[i]     += f0 + f2;
            ksp[4 + i] += f1 + f3;
            const int dl = 4 * c + i, dh = 32 + 4 * c + i;
            const int wl = swz_slot(dl, pr >> 2) * 4 + (pr & 3);
            const int wh = swz_slot(dh, pr >> 2) * 4 + (pr & 3);
            Kb[buf][dl][wl] = cvt_pk_bf16(f0, f2);      // lo = even s
            Kb[buf][dh][wh] = cvt_pk_bf16(f1, f3);
            Vb[buf][dl][wl] = cvt_pk_bf16(b0[i], b2[i]);
            Vb[buf][dh][wh] = cvt_pk_bf16(b1[i], b3[i]);
        }

        __syncthreads();   // free drain: all loads already consumed by STORE

        if (ch + 1 < NCHK_) {              // issue next chunk's loads NOW;
            const size_t nb = rbase + (size_t)(ch + 1) * CHR_ * STRIDE_;
            kr0 = *(const float4*)(keys + nb);          // they stay in flight
            kr1 = *(const float4*)(keys + nb + 32);     // across COMPUTE and
            kr2 = *(const float4*)(keys + nb + STRIDE_);// are consumed by the
            kr3 = *(const float4*)(keys + nb + STRIDE_ + 32); // next STORE's
            vr0 = *(const float4*)(values + nb);        // counted vmcnt wait
            vr1 = *(const float4*)(values + nb + 32);
            vr2 = *(const float4*)(values + nb + STRIDE_);
            vr3 = *(const float4*)(values + nb + STRIDE_ + 32);
        }

        const int rk = 32 * wd + lm, rv = 32 * wm + lm;
        #pragma unroll
        for (int m = 0; m < 4; ++m) {
            const int sa = ((2 * m + lh) ^ (lm & 7) ^ (lm >> 2)) & 7;
            bf16x8 af = *(const bf16x8*)&Kb[buf][rk][sa * 4];
            bf16x8 bv = *(const bf16x8*)&Vb[buf][rv][sa * 4];
            acc = __builtin_amdgcn_mfma_f32_32x32x16_bf16(af, bv, acc, 0, 0, 0);
        }
    }

    // C/D layout (m74/m101): col=lane&31, row=(r&3)+8*(r>>2)+4*(lane>>5)
    float* dst = pkv + (size_t)blk * (E_ * E_);
    #pragma unroll
    for (int r = 0; r < 16; ++r) {
        const int ro = (r & 3) + 8 * (r >> 2) + 4 * lh;
        dst[(32 * wd + ro) * E_ + 32 * wm + lm] = acc[r];
    }

    // ksum: per-thread partials [8] -> LDS scratch (reuse Kb[0]) -> reduce
    __syncthreads();
    float* ksb = (float*)&Kb[0][0][0];     // [256][8] f32 = 8 KB
    *(float4*)&ksb[t * 8]     = make_float4(ksp[0], ksp[1], ksp[2], ksp[3]);
    *(float4*)&ksb[t * 8 + 4] = make_float4(ksp[4], ksp[5], ksp[6], ksp[7]);
    __syncthreads();
    if (t < E_) {
        const int cc = (t & 31) >> 2, e = (t >> 5) * 4 + (t & 3);
        float s = 0.f;
        #pragma unroll
        for (int pp = 0; pp < 32; ++pp) s += ksb[(pp * 8 + cc) * 8 + e];
        pks[(size_t)blk * E_ + t] = s;
    }
}

// ---------------------------------------------------------------------------
// Reduce: KV[d][m] = sum_c pkv; emit KV^T bf16 [m][d] + ksum f32.
// ---------------------------------------------------------------------------
__global__ __launch_bounds__(256) void la_reduce(
    const float* __restrict__ pkv, const float* __restrict__ pks,
    unsigned short* __restrict__ kvt, float* __restrict__ ksum)
{
    const int b = blockIdx.x, nh = b >> 4, sl = b & 15;
    const int e = sl * 256 + threadIdx.x;          // e = d*64 + m
    const float* src = pkv + (size_t)nh * SPLIT_ * (E_ * E_) + e;
    float s = 0.f;
    #pragma unroll
    for (int c = 0; c < SPLIT_; ++c) s += src[(size_t)c * (E_ * E_)];
    const int d = e >> 6, m = e & 63;
    kvt[(size_t)nh * (E_ * E_) + m * E_ + d] = f2bf(s);

    if (sl == 0 && threadIdx.x < E_) {
        const float* sp = pks + (size_t)nh * SPLIT_ * E_ + threadIdx.x;
        float ss = 0.f;
        #pragma unroll
        for (int c = 0; c < SPLIT_; ++c) ss += sp[c * E_];
        ksum[nh * E_ + threadIdx.x] = ss;
    }
}

// ---------------------------------------------------------------------------
// Phase 2: out[l][m] = z[l] * sum_d qf[l,d]*KV[d,m] via MFMA (r8, unchanged).
// ---------------------------------------------------------------------------
__global__ __launch_bounds__(256) void la_out(
    const float* __restrict__ q, const unsigned short* __restrict__ kvt,
    const float* __restrict__ ksum, float* __restrict__ out)
{
    const int blk = blockIdx.x, nh = blk >> 5, tile = blk & 31;
    const int n = nh / H_, h = nh % H_;
    const int t = threadIdx.x, l = t & 63, w = t >> 6;
    const int lm = l & 31, lh = l >> 5;

    __shared__ float zbuf[4][32];

    const unsigned short* kb = kvt + (size_t)nh * (E_ * E_);
    const float* ks = ksum + nh * E_;

    bf16x8 bfr[4][2];
    float4 kr[4][2];
    #pragma unroll
    for (int st = 0; st < 4; ++st) {
        #pragma unroll
        for (int c = 0; c < 2; ++c)
            bfr[st][c] = *(const bf16x8*)&kb[(32 * c + lm) * E_ + st * 16 + 8 * lh];
        kr[st][0] = *(const float4*)&ks[st * 16 + 8 * lh];
        kr[st][1] = *(const float4*)&ks[st * 16 + 8 * lh + 4];
    }

    const size_t base = (size_t)n * (L_ * H_ * E_) + (size_t)h * E_;

    #pragma unroll
    for (int bnd = 0; bnd < 2; ++bnd) {
        const int l0 = tile * 256 + w * 64 + bnd * 32;
        const float* qp = q + base + (size_t)(l0 + lm) * STRIDE_ + 8 * lh;

        float4 qa[4], qb[4];
        #pragma unroll
        for (int st = 0; st < 4; ++st) {
            qa[st] = *(const float4*)(qp + st * 16);
            qb[st] = *(const float4*)(qp + st * 16 + 4);
        }

        float zd = 0.f;
        bf16x8 af[4];
        #pragma unroll
        for (int st = 0; st < 4; ++st) {
            const float f0 = featmap(qa[st].x), f1 = featmap(qa[st].y),
                        f2 = featmap(qa[st].z), f3 = featmap(qa[st].w);
            const float g0 = featmap(qb[st].x), g1 = featmap(qb[st].y),
                        g2 = featmap(qb[st].z), g3 = featmap(qb[st].w);
            zd += f0 * kr[st][0].x + f1 * kr[st][0].y + f2 * kr[st][0].z + f3 * kr[st][0].w
                + g0 * kr[st][1].x + g1 * kr[st][1].y + g2 * kr[st][1].z + g3 * kr[st][1].w;
            union { bf16x8 v; unsigned u[4]; } a;
            a.u[0] = cvt_pk_bf16(f0, f1);
            a.u[1] = cvt_pk_bf16(f2, f3);
            a.u[2] = cvt_pk_bf16(g0, g1);
            a.u[3] = cvt_pk_bf16(g2, g3);
            af[st] = a.v;
        }
        zd += __shfl_xor(zd, 32);
        const float z = 1.0f / (zd + 1e-6f);
        if (l < 32) zbuf[w][l] = z;
        __builtin_amdgcn_wave_barrier();

        f32x16 c0 = {0,0,0,0,0,0,0,0,0,0,0,0,0,0,0,0};
        f32x16 c1 = {0,0,0,0,0,0,0,0,0,0,0,0,0,0,0,0};
        #pragma unroll
        for (int st = 0; st < 4; ++st) {
            c0 = __builtin_amdgcn_mfma_f32_32x32x16_bf16(af[st], bfr[st][0], c0, 0, 0, 0);
            c1 = __builtin_amdgcn_mfma_f32_32x32x16_bf16(af[st], bfr[st][1], c1, 0, 0, 0);
        }

        float* op = out + base + (size_t)l0 * STRIDE_ + lm;
        #pragma unroll
        for (int r = 0; r < 16; ++r) {
            const int ro = (r & 3) + 8 * (r >> 2) + 4 * lh;
            const float zz = zbuf[w][ro];
            op[(size_t)ro * STRIDE_]      = c0[r] * zz;
            op[(size_t)ro * STRIDE_ + 32] = c1[r] * zz;
        }
        __builtin_amdgcn_wave_barrier();   // zbuf reused next band
    }
}

extern "C" void kernel_launch(void* const* d_in, const int* in_sizes, int n_in,
                              void* d_out, int out_size, void* d_ws, size_t ws_size,
                              hipStream_t stream) {
    (void)in_sizes; (void)n_in; (void)out_size; (void)ws_size;
    const float* qq = (const float*)d_in[0];
    const float* kk = (const float*)d_in[1];
    const float* vv = (const float*)d_in[2];
    float* outp = (float*)d_out;
    float* ws   = (float*)d_ws;

    float* pkv = ws;
    float* pks = ws + (size_t)NH_ * SPLIT_ * (E_ * E_);
    unsigned short* kvt = (unsigned short*)(pks + (size_t)NH_ * SPLIT_ * E_);
    float* ksm = (float*)(kvt + (size_t)NH_ * (E_ * E_));

    la_kv<<<NH_ * SPLIT_, 256, 0, stream>>>(kk, vv, pkv, pks);
    la_reduce<<<NH_ * 16, 256, 0, stream>>>(pkv, pks, kvt, ksm);
    la_out<<<NH_ * 32, 256, 0, stream>>>(qq, kvt, ksm, outp);
}